// Round 11
// baseline (119.129 us; speedup 1.0000x reference)
//
#include <hip/hip_runtime.h>

// Problem constants (from reference setup_inputs)
#define N_  16
#define C_  64
#define H_  128
#define W_  128
#define HO_ 64
#define WO_ 64
#define CO_ 18     // G*K*K = 2*3*3
#define NSP 8      // channel splits (= waves per block)
#define CPS (C_/NSP)
#define WPAD 12    // padded weights per (c,o): 48B, 16B-aligned
#define WTOT (C_*CO_*WPAD)   // 13824 floats

// ws: [0..13823] cwT[c*216 + o*12 + k] = cw[o*576+c*9+k]*inv[o] (k<9, else 0)
//     [13824..13841] shift[o] = beta[o] - mean[o]*inv[o]
__global__ void pasa_prep(const float* __restrict__ cw,
                          const float* __restrict__ gamma,
                          const float* __restrict__ beta,
                          const float* __restrict__ mean,
                          const float* __restrict__ var,
                          float* __restrict__ ws)
{
    const int i = blockIdx.x * 256 + threadIdx.x;
    if (i < WTOT) {
        const int k = i % WPAD;
        const int o = (i / WPAD) % CO_;
        const int c = i / (WPAD * CO_);
        const float inv = gamma[o] * rsqrtf(var[o] + 1e-5f);
        ws[i] = (k < 9) ? cw[o * (C_*9) + c * 9 + k] * inv : 0.f;
    }
    if (i < CO_) {
        const float inv = gamma[i] * rsqrtf(var[i] + 1e-5f);
        ws[WTOT + i] = beta[i] - mean[i] * inv;
    }
}

__global__ __launch_bounds__(512)
void pasa_main(const float* __restrict__ x,
               const float* __restrict__ wt,    // = ws
               float* __restrict__ out)
{
    // partial logits only: [sp][wo][o] = 36864 B -> 4 blocks/CU
    __shared__ float part[NSP][WO_][CO_];

    const int tid = threadIdx.x;
    const int wo  = tid & 63;
    const int sp  = tid >> 6;
    // XCD-chunk swizzle: XCD = bx & 7; each XCD gets 8 contiguous ho rows.
    const int bx  = blockIdx.x;
    const int ho  = ((bx & 7) << 3) | (bx >> 3);
    const int n   = blockIdx.y;

    // 3x3 window at input (2ho, 2wo), reflect pad=1 (only -1 reachable -> +1)
    int r0 = 2*ho - 1; if (r0 < 0) r0 = 1;
    const int r1 = 2*ho, r2 = 2*ho + 1;
    const int c1 = 2*wo;
    int c0 = c1 - 1; if (c0 < 0) c0 = 1;

    const float* __restrict__ xn    = x  + (size_t)n * (C_*H_*W_);
    const float* __restrict__ shift = wt + WTOT;

    float sig[CO_];
#pragma unroll
    for (int o = 0; o < CO_; ++o) sig[o] = 0.f;

    // Pass 1: per channel j: 9 window loads + 18x9 FMA. Weights come through
    // the VECTOR memory pipe (no readfirstlane -> compiler can't prove
    // uniformity -> global_load_dwordx4, deep vmcnt pipelining; each load is
    // one L1 access broadcast to 64 lanes; 41KB weight array is L1/L2-hot).
#pragma unroll
    for (int j = 0; j < CPS; ++j) {
        const int c = sp * CPS + j;
        const float* __restrict__ xc = xn + c * (H_*W_);
        const float  w0  = xc[r0*W_ + c0];
        const float2 t01 = *(const float2*)(xc + r0*W_ + c1);
        const float  w3  = xc[r1*W_ + c0];
        const float2 t45 = *(const float2*)(xc + r1*W_ + c1);
        const float  w6  = xc[r2*W_ + c0];
        const float2 t78 = *(const float2*)(xc + r2*W_ + c1);
        const float* __restrict__ q = wt + c * (CO_*WPAD);   // 16B-aligned
#pragma unroll
        for (int o = 0; o < CO_; ++o) {
            const float4 A = *(const float4*)(q + o*WPAD);      // dwordx4
            const float4 B = *(const float4*)(q + o*WPAD + 4);  // dwordx4
            const float  E = q[o*WPAD + 8];                     // dword
            float a = sig[o];
            a = fmaf(w0,    A.x, a);
            a = fmaf(t01.x, A.y, a);
            a = fmaf(t01.y, A.z, a);
            a = fmaf(w3,    A.w, a);
            a = fmaf(t45.x, B.x, a);
            a = fmaf(t45.y, B.y, a);
            a = fmaf(w6,    B.z, a);
            a = fmaf(t78.x, B.w, a);
            a = fmaf(t78.y, E,   a);
            sig[o] = a;
        }
    }

    // Tree-reduce the 8 wave partials through LDS (float2 granularity).
#pragma unroll
    for (int i = 0; i < 9; ++i)
        *(float2*)&part[sp][wo][2*i] = make_float2(sig[2*i], sig[2*i+1]);
    __syncthreads();
    if (sp < 4) {
#pragma unroll
        for (int i = 0; i < 9; ++i) {
            const float2 a = *(const float2*)&part[sp+4][wo][2*i];
            float2* d = (float2*)&part[sp][wo][2*i];
            float2 b = *d; b.x += a.x; b.y += a.y; *d = b;
        }
    }
    __syncthreads();
    if (sp < 2) {
#pragma unroll
        for (int i = 0; i < 9; ++i) {
            const float2 a = *(const float2*)&part[sp+2][wo][2*i];
            float2* d = (float2*)&part[sp][wo][2*i];
            float2 b = *d; b.x += a.x; b.y += a.y; *d = b;
        }
    }
    __syncthreads();
    if (sp == 0) {
#pragma unroll
        for (int i = 0; i < 9; ++i) {
            const float2 a = *(const float2*)&part[1][wo][2*i];
            float2* d = (float2*)&part[0][wo][2*i];
            float2 b = *d; b.x += a.x; b.y += a.y; *d = b;
        }
    }
    __syncthreads();

    // BN shift + softmax over 18, redundant per thread (cheap).
    float mx = -3.4e38f;
#pragma unroll
    for (int i = 0; i < 9; ++i) {
        const float2 a = *(const float2*)&part[0][wo][2*i];
        sig[2*i]   = a.x + shift[2*i];
        sig[2*i+1] = a.y + shift[2*i+1];
    }
#pragma unroll
    for (int o = 0; o < CO_; ++o) mx = fmaxf(mx, sig[o]);
    float sum = 0.f;
#pragma unroll
    for (int o = 0; o < CO_; ++o) { sig[o] = __expf(sig[o] - mx); sum += sig[o]; }
    const float rs = 1.f / sum;

    // Group-select with compile-time sig[] indices (sp>>2 is wave-uniform)
    float p[9];
    if ((sp >> 2) == 0) {
#pragma unroll
        for (int k = 0; k < 9; ++k) p[k] = sig[k] * rs;
    } else {
#pragma unroll
        for (int k = 0; k < 9; ++k) p[k] = sig[9 + k] * rs;
    }

    // Pass 2: aggregation; windows re-loaded (L1-hot).
#pragma unroll
    for (int j = 0; j < CPS; ++j) {
        const int c = sp * CPS + j;
        const float* __restrict__ xc = xn + c * (H_*W_);
        float acc = xc[r0*W_ + c0] * p[0];
        const float2 a12 = *(const float2*)(xc + r0*W_ + c1);
        acc = fmaf(a12.x, p[1], acc);
        acc = fmaf(a12.y, p[2], acc);
        acc = fmaf(xc[r1*W_ + c0], p[3], acc);
        const float2 a45 = *(const float2*)(xc + r1*W_ + c1);
        acc = fmaf(a45.x, p[4], acc);
        acc = fmaf(a45.y, p[5], acc);
        acc = fmaf(xc[r2*W_ + c0], p[6], acc);
        const float2 a78 = *(const float2*)(xc + r2*W_ + c1);
        acc = fmaf(a78.x, p[7], acc);
        acc = fmaf(a78.y, p[8], acc);
        out[(((size_t)n*C_ + c)*HO_ + ho)*WO_ + wo] = acc;
    }
}

extern "C" void kernel_launch(void* const* d_in, const int* in_sizes, int n_in,
                              void* d_out, int out_size, void* d_ws, size_t ws_size,
                              hipStream_t stream) {
    const float* x     = (const float*)d_in[0];
    const float* cw    = (const float*)d_in[1];
    const float* gamma = (const float*)d_in[2];
    const float* beta  = (const float*)d_in[3];
    const float* mean  = (const float*)d_in[4];
    const float* var   = (const float*)d_in[5];
    float* out = (float*)d_out;
    float* ws  = (float*)d_ws;   // needs (13824+18)*4 B

    pasa_prep<<<(WTOT + 255) / 256, 256, 0, stream>>>(cw, gamma, beta, mean, var, ws);
    dim3 grid(HO_, N_);   // 64 ho-rows x 16 batch, 8 waves/block
    pasa_main<<<grid, 512, 0, stream>>>(x, ws, out);
}

// Round 13
// 44.679 us; speedup vs baseline: 2.6663x; 2.6663x over previous
//
#include <hip/hip_runtime.h>

// Problem constants
#define N_  16
#define C_  64
#define H_  128
#define W_  128
#define HO_ 64
#define WO_ 64
#define CO_ 18

// WT geometry: 20 rows (18 + 2 zero) x 584 f16, padded to 128B multiple
#define BK     584
#define BROWS  20
#define BBYTES_PAD 23424             // ceil(20*584*2 / 128)*128
#define NSHORT (BBYTES_PAD/2)        // 11712 (pad shorts zeroed by prep)
#define AOFF   BBYTES_PAD            // 23424 -> 128-byte aligned A cells
#define SIGOFF (AOFF + 3*128*128)    // 23424 + 49152 = 72576
#define LDSBYTES (SIGOFF + 64*21*4)  // 77952 < 81920 -> 2 blocks/CU
#define SHIFTOFF BBYTES_PAD          // byte offset of shift[18] in ws

typedef _Float16 f16;
typedef f16 f16x4 __attribute__((ext_vector_type(4)));
typedef f16 f16x8 __attribute__((ext_vector_type(8)));
typedef float f4v  __attribute__((ext_vector_type(4)));

// ws: [0..23423B)  WT f16 [20][584]: WT[o][tap*64+c] = cw[o,c,tap]*inv[o]
//     (rows>=18, k>=576, and pad region all ZERO)
//     [23424B..)   shift fp32 [18] = beta - mean*inv
__global__ void pasa_prep(const float* __restrict__ cw,
                          const float* __restrict__ gamma,
                          const float* __restrict__ beta,
                          const float* __restrict__ mean,
                          const float* __restrict__ var,
                          float* __restrict__ ws)
{
    const int i = blockIdx.x * 256 + threadIdx.x;
    if (i < NSHORT) {
        const int o = i / BK, kk = i % BK;
        unsigned short bits = 0;
        if (o < CO_ && kk < 576) {
            const int tap = kk >> 6, c = kk & 63;   // k = tap*64 + c
            const float inv = gamma[o] * rsqrtf(var[o] + 1e-5f);
            const f16 h = (f16)(cw[o*576 + c*9 + tap] * inv);
            bits = *(const unsigned short*)&h;
        }
        ((unsigned short*)ws)[i] = bits;
    }
    if (i < CO_) {
        const float inv = gamma[i] * rsqrtf(var[i] + 1e-5f);
        *(float*)((char*)ws + SHIFTOFF + i*4) = beta[i] - mean[i] * inv;
    }
}

__global__ __launch_bounds__(512)
void pasa_main(const float* __restrict__ x,
               const float* __restrict__ wt,
               float* __restrict__ out)
{
    __shared__ __align__(128) char lds[LDSBYTES];

    const int tid  = threadIdx.x;
    const int lane = tid & 63;
    const int bx = blockIdx.x;
    const int ho = ((bx & 7) << 3) | (bx >> 3);   // XCD-chunk swizzle
    const int n  = blockIdx.y;

    int r0 = 2*ho - 1; if (r0 < 0) r0 = 1;        // reflect pad
    const int r1 = 2*ho, r2 = 2*ho + 1;
    const float* __restrict__ xn = x + (size_t)n * (C_*H_*W_);

    // P0a: WT (incl. zero pad) -> LDS
    {
        const unsigned* __restrict__ src = (const unsigned*)wt;
        unsigned* dst = (unsigned*)lds;
        for (int i = tid; i < BBYTES_PAD/4; i += 512) dst[i] = src[i];
    }
    // P0b: stage A: cell(y,xcol) = 64 channels f16 (128B, channel-straight),
    // XOR-swizzled in 16B slots; cells 128B-aligned -> XOR is a bijection.
    if (tid < 384) {
        const int y    = tid >> 7;
        const int xcol = tid & 127;
        const int row  = (y == 0) ? r0 : (y == 1 ? r1 : r2);
        const float* __restrict__ bse = xn + row*W_ + xcol;
        char* cell = lds + AOFF + ((y*128 + xcol) << 7);
        const int sw = ((xcol >> 1) & 7) << 4;
        #pragma unroll
        for (int s = 0; s < 8; ++s) {             // slot s = channels 8s..8s+7
            f16x8 v;
            #pragma unroll
            for (int t = 0; t < 8; ++t)
                v[t] = (f16)bse[(8*s + t) * (H_*W_)];
            *(f16x8*)(cell + ((s*16) ^ sw)) = v;  // b128, even bank coverage
        }
    }
    __syncthreads();

    // P1: 36 x v_mfma_f32_16x16x16f16 (classic layout: A row=l&15,k=4*lg+i;
    // B col=l&15,k=4*lg+i; D col=l&15,row=4*lg+r [m89]).
    const int wv = tid >> 6;
    const int mt = wv >> 1, nt = wv & 1;          // 4 M-tiles x 2 N-tiles
    const int p  = lane & 15, lg = lane >> 4;

    int xcA[3], swA[3];
    #pragma unroll
    for (int kj = 0; kj < 3; ++kj) {
        int xc = 32*mt + 2*p + kj - 1; if (xc < 0) xc = 1;  // reflect
        xcA[kj] = xc; swA[kj] = ((xc >> 1) & 7) << 4;
    }
    const int o    = nt*16 + p;
    const int oeff = (o < BROWS) ? o : 18;        // rows>=20 -> zeroed row
    const char* __restrict__ brow = lds + oeff*(BK*2) + lg*8;

    f4v acc = {0.f, 0.f, 0.f, 0.f};
    #pragma unroll
    for (int ki = 0; ki < 3; ++ki) {
        #pragma unroll
        for (int kj = 0; kj < 3; ++kj) {
            const char* __restrict__ abase = lds + AOFF + ((ki*128 + xcA[kj]) << 7);
            const int sw = swA[kj];
            #pragma unroll
            for (int kc = 0; kc < 4; ++kc) {      // 4 x 16-channel chunks
                const f16x4 a = *(const f16x4*)(abase + ((kc*32 + lg*8) ^ sw));
                const f16x4 b = *(const f16x4*)(brow + (ki*3 + kj)*128 + kc*32);
                acc = __builtin_amdgcn_mfma_f32_16x16x16f16(a, b, acc, 0, 0, 0);
            }
        }
    }

    // P2: D -> sigma LDS [64 pos][21] (pad 21: gcd(21,32)=1, conflict-free)
    {
        float* sig_lds = (float*)(lds + SIGOFF);
        if (o < CO_) {
            #pragma unroll
            for (int r = 0; r < 4; ++r)
                sig_lds[(mt*16 + lg*4 + r)*21 + o] = acc[r];
        }
    }
    __syncthreads();

    // P3: softmax over 18 (redundant per thread), fp32
    const int wo = tid & 63;
    const int sp = tid >> 6;
    const float* __restrict__ shift = (const float*)((const char*)wt + SHIFTOFF);
    const float* sig_lds = (const float*)(lds + SIGOFF);

    float sig[CO_];
    float mx = -3.4e38f;
    #pragma unroll
    for (int oo = 0; oo < CO_; ++oo) {
        sig[oo] = sig_lds[wo*21 + oo] + shift[oo];
        mx = fmaxf(mx, sig[oo]);
    }
    float sum = 0.f;
    #pragma unroll
    for (int oo = 0; oo < CO_; ++oo) { sig[oo] = __expf(sig[oo] - mx); sum += sig[oo]; }
    const float rs = 1.f / sum;

    float pw[9];
    if ((sp >> 2) == 0) {
        #pragma unroll
        for (int k = 0; k < 9; ++k) pw[k] = sig[k] * rs;
    } else {
        #pragma unroll
        for (int k = 0; k < 9; ++k) pw[k] = sig[9 + k] * rs;
    }

    // P4: aggregation from global fp32 windows (L1/L2-hot), 8 ch per thread
    const int c1 = 2*wo;
    int c0 = c1 - 1; if (c0 < 0) c0 = 1;
    #pragma unroll
    for (int j = 0; j < 8; ++j) {
        const int c = sp * 8 + j;
        const float* __restrict__ xc = xn + c * (H_*W_);
        float a = xc[r0*W_ + c0] * pw[0];
        const float2 a12 = *(const float2*)(xc + r0*W_ + c1);
        a = fmaf(a12.x, pw[1], a);
        a = fmaf(a12.y, pw[2], a);
        a = fmaf(xc[r1*W_ + c0], pw[3], a);
        const float2 a45 = *(const float2*)(xc + r1*W_ + c1);
        a = fmaf(a45.x, pw[4], a);
        a = fmaf(a45.y, pw[5], a);
        a = fmaf(xc[r2*W_ + c0], pw[6], a);
        const float2 a78 = *(const float2*)(xc + r2*W_ + c1);
        a = fmaf(a78.x, pw[7], a);
        a = fmaf(a78.y, pw[8], a);
        out[(((size_t)n*C_ + c)*HO_ + ho)*WO_ + wo] = a;
    }
}

extern "C" void kernel_launch(void* const* d_in, const int* in_sizes, int n_in,
                              void* d_out, int out_size, void* d_ws, size_t ws_size,
                              hipStream_t stream) {
    const float* x     = (const float*)d_in[0];
    const float* cw    = (const float*)d_in[1];
    const float* gamma = (const float*)d_in[2];
    const float* beta  = (const float*)d_in[3];
    const float* mean  = (const float*)d_in[4];
    const float* var   = (const float*)d_in[5];
    float* out = (float*)d_out;
    float* ws  = (float*)d_ws;   // needs 23424 + 72 B

    pasa_prep<<<(NSHORT + 255) / 256, 256, 0, stream>>>(cw, gamma, beta, mean, var, ws);
    dim3 grid(HO_, N_);
    pasa_main<<<grid, 512, 0, stream>>>(x, ws, out);
}